// Round 8
// baseline (405.249 us; speedup 1.0000x reference)
//
#include <hip/hip_runtime.h>
#include <hip/hip_bf16.h>

#define DIM 64
#define NREL 8
#define KS 512              // Sx width (k-permuted: k = ch*8 + r)
#define KTOT 576            // GEMM K: 512 + 64 root
#define PADK 520            // LDS row stride in bf16 (1040B) -> uniform bank spread

typedef __bf16 bf16x8 __attribute__((ext_vector_type(8)));
typedef __bf16 bf16x4 __attribute__((ext_vector_type(4)));
typedef float  f32x4  __attribute__((ext_vector_type(4)));

// ---------------- fused: hist (rank-returning) + initial gather + sentinels ----------------
__global__ __launch_bounds__(256) void histgather_kernel(const int* __restrict__ dst,
                                                         const int* __restrict__ et,
                                                         int* __restrict__ deg8,
                                                         int* __restrict__ eoff,
                                                         const int* __restrict__ x_idx,
                                                         const float* __restrict__ emb,
                                                         __bf16* __restrict__ xb0,
                                                         __bf16* __restrict__ xb1,
                                                         int* __restrict__ srcs,
                                                         int N, int E, int epad_cap) {
    int i = blockIdx.x * 256 + threadIdx.x;
    if (i < N * DIM) {
        int n = i >> 6;
        int c = i & 63;
        xb0[i] = (__bf16)emb[(size_t)x_idx[n] * DIM + c];
    }
    if (i < DIM) {                                        // sentinel zero rows (node index N)
        xb0[(size_t)N * DIM + i] = (__bf16)0.f;
        xb1[(size_t)N * DIM + i] = (__bf16)0.f;
    }
    if (i < epad_cap) srcs[i] = N * NREL;                 // padding -> sentinel gidx (src=N, rel=0)
    if (i < E) eoff[i] = atomicAdd(&deg8[dst[i] * 8 + et[i]], 1);  // rank within (dst,rel) cell
}

// ---------------- scan1 over per-dst ROW-PADDED totals + invdeg (true deg) ----------------
__global__ __launch_bounds__(256) void scan1_kernel(const int* __restrict__ deg8,
                                                    int* __restrict__ offs,
                                                    int* __restrict__ bsum,
                                                    float* __restrict__ invdeg, int N) {
    __shared__ int sd[256];
    int tid = threadIdx.x;
    int d = blockIdx.x * 256 + tid;
    int vpad = 0;
    if (d < N) {
        int vtrue = 0;
#pragma unroll
        for (int r = 0; r < NREL; ++r) vtrue += deg8[d * 8 + r];
        vpad = (vtrue + 3) & ~3;                          // pad per ROW
        invdeg[d] = 1.0f / fmaxf((float)vtrue, 1.0f);
    }
    sd[tid] = vpad;
    __syncthreads();
#pragma unroll
    for (int off = 1; off < 256; off <<= 1) {
        int t = (tid >= off) ? sd[tid - off] : 0;
        __syncthreads();
        sd[tid] += t;
        __syncthreads();
    }
    if (d < N) offs[d] = sd[tid] - vpad;
    if (tid == 255) bsum[blockIdx.x] = sd[255];
}

// ---------------- scan2 (block 0) + wcat (blocks >= 1) fused ----------------
// Wt[l][c][k]: k<512 -> k=ch*8+r maps weight[l][r][ch][c]; k>=512 -> root[l][k-512][c]
__global__ __launch_bounds__(512) void scan2wcat_kernel(int* __restrict__ bsum, int nb,
                                                        const float* __restrict__ weight,
                                                        const float* __restrict__ root,
                                                        __bf16* __restrict__ Wt, int L) {
    if (blockIdx.x == 0) {
        __shared__ int sd[512];
        int tid = threadIdx.x;
        int v = (tid < nb) ? bsum[tid] : 0;
        sd[tid] = v;
        __syncthreads();
#pragma unroll
        for (int off = 1; off < 512; off <<= 1) {
            int t = (tid >= off) ? sd[tid - off] : 0;
            __syncthreads();
            sd[tid] += t;
            __syncthreads();
        }
        if (tid < nb) bsum[tid] = sd[tid] - v;
    } else {
        int idx = (blockIdx.x - 1) * 512 + threadIdx.x;
        int total = L * 64 * KTOT;
        if (idx >= total) return;
        int l = idx / (64 * KTOT);
        int rem = idx - l * 64 * KTOT;
        int c = rem / KTOT;
        int k = rem - c * KTOT;
        float w;
        if (k < KS) {
            int ch = k >> 3, r = k & 7;
            w = weight[(((l * 8 + r) * 64) + ch) * 64 + c];
        } else {
            w = root[(l * 64 + (k - KS)) * 64 + c];
        }
        Wt[idx] = (__bf16)w;
    }
}

// ---------------- rp build: exact cell starts within row-padded slot space ----------------
__global__ __launch_bounds__(256) void rpbuild_kernel(const int* __restrict__ deg8,
                                                      const int* __restrict__ offs,
                                                      const int* __restrict__ bsum,
                                                      int* __restrict__ rp,
                                                      int N) {
    int d = blockIdx.x * 256 + threadIdx.x;
    if (d >= N) return;
    int base = offs[d] + bsum[blockIdx.x];
    int run = 0;
#pragma unroll
    for (int r = 0; r < NREL; ++r) {
        rp[d * 8 + r] = base + run;
        run += deg8[d * 8 + r];                           // exact (no per-cell pad)
    }
    if (d == N - 1) rp[(size_t)N * 8] = base + ((run + 3) & ~3);   // padded total
}

// ---------------- bucket: atomic-free scatter of PACKED gather index src*8+rel ----------------
__global__ __launch_bounds__(256) void bucket_kernel(const int* __restrict__ src,
                                                     const int* __restrict__ dst,
                                                     const int* __restrict__ et,
                                                     const int* __restrict__ rp,
                                                     const int* __restrict__ eoff,
                                                     int* __restrict__ srcs, int E) {
    int i = blockIdx.x * 256 + threadIdx.x;
    int half = (E + 1) >> 1;
    if (i >= half) return;
    int iB = i + half;
    bool hasB = iB < E;
    int etA = et[i];
    int etB = hasB ? et[iB] : 0;
    int cellA = dst[i] * 8 + etA;
    int cellB = hasB ? dst[iB] * 8 + etB : 0;
    int rA = rp[cellA];
    int rB = hasB ? rp[cellB] : 0;
    int oA = eoff[i];
    int oB = hasB ? eoff[iB] : 0;
    int sA = src[i];
    int sB = hasB ? src[iB] : 0;
    srcs[rA + oA] = sA * NREL + etA;                      // packed gidx
    if (hasB) srcs[rB + oB] = sB * NREL + etB;
}

// uniform (scalar) rel branch-tree: one v_add into a named accumulator
#define ACC(r_, v_) { int _r = (r_); float _v = (v_);                          \
    if (_r < 4) { if (_r < 2) { if (_r == 0) f0 += _v; else f1 += _v; }        \
                  else        { if (_r == 2) f2 += _v; else f3 += _v; } }      \
    else        { if (_r < 6) { if (_r == 4) f4 += _v; else f5 += _v; }        \
                  else        { if (_r == 6) f6 += _v; else f7 += _v; } } }

// ---------------- aggemm2: single-loop rel-tracked aggregation + fused rel/root GEMM ----
// Phase A: wave w handles 4 dst rows; ONE loop over the row's padded slots; gather x[src]
//   (12.8MB, L2/L3-hot) and route each value into f0..f7 via a UNIFORM branch tree
//   (slot gidx is s_load'd -> rel is scalar; no divergence, no LDS, no scratch).
//   Writes k-permuted Sx row (k = ch*8 + r) to LDS.
// Phase B: round-3-verified GEMM: W-in-registers (A), Sx from LDS + x root term (B), K=576.
// xout MUST NOT alias xin (gathers read other nodes' rows while xnxt is written).
__global__ __launch_bounds__(256) void aggemm2_kernel(const __bf16* __restrict__ xb,
                                                      const int* __restrict__ srcs,
                                                      const int* __restrict__ rp,
                                                      const float* __restrict__ invdeg,
                                                      const __bf16* __restrict__ Wt,    // [64][576]
                                                      const float* __restrict__ bias_l, // [64]
                                                      __bf16* __restrict__ xout, int N) {
    __shared__ __align__(16) __bf16 S[16 * PADK];
    int wave = threadIdx.x >> 6;
    int lane = threadIdx.x & 63;
    int l15 = lane & 15;
    int lg  = lane >> 4;
    const int SENT = N * NREL;                            // sentinel gidx (src=N zero row, rel=0)

    // hoist A (weights) into registers once per block: 18 x 4 VGPRs = 72 VGPRs
    bf16x8 afrag[KTOT / 32];
    {
        const __bf16* wrow = Wt + (size_t)(16 * wave + l15) * KTOT + lg * 8;
#pragma unroll
        for (int kk = 0; kk < KTOT / 32; ++kk)
            afrag[kk] = *reinterpret_cast<const bf16x8*>(wrow + kk * 32);
    }
    int cbase = 16 * wave + 4 * lg;
    f32x4 bias4 = *reinterpret_cast<const f32x4*>(bias_l + cbase);

    int ntiles = (N + 15) >> 4;
    for (int tile = blockIdx.x; tile < ntiles; tile += gridDim.x) {
        // ---------- phase A ----------
#pragma unroll
        for (int rr = 0; rr < 4; ++rr) {
            int d0 = tile * 16 + wave * 4 + rr;
            if (d0 >= N) d0 = N - 1;                      // tail tile only
            int d = __builtin_amdgcn_readfirstlane(d0);
            int qb = rp[d * 8];
            int qe = rp[d * 8 + 8];                       // next row base = padded end
            float f0 = 0.f, f1 = 0.f, f2 = 0.f, f3 = 0.f;
            float f4 = 0.f, f5 = 0.f, f6 = 0.f, f7 = 0.f;
            for (int q = qb; q < qe; q += 8) {            // 8 gathers in flight
                int rem = qe - q;                         // multiple of 4
                int4 sa = *reinterpret_cast<const int4*>(srcs + q);
                int4 sb = *reinterpret_cast<const int4*>(srcs + q + 4);
                bool vb = rem >= 8;                       // over-read stays in +64 slack
                int g0 = sa.x, g1 = sa.y, g2 = sa.z, g3 = sa.w;
                int g4 = vb ? sb.x : SENT, g5 = vb ? sb.y : SENT;
                int g6 = vb ? sb.z : SENT, g7 = vb ? sb.w : SENT;
                float v0 = (float)xb[(size_t)(g0 >> 3) * DIM + lane];
                float v1 = (float)xb[(size_t)(g1 >> 3) * DIM + lane];
                float v2 = (float)xb[(size_t)(g2 >> 3) * DIM + lane];
                float v3 = (float)xb[(size_t)(g3 >> 3) * DIM + lane];
                float v4 = (float)xb[(size_t)(g4 >> 3) * DIM + lane];
                float v5 = (float)xb[(size_t)(g5 >> 3) * DIM + lane];
                float v6 = (float)xb[(size_t)(g6 >> 3) * DIM + lane];
                float v7 = (float)xb[(size_t)(g7 >> 3) * DIM + lane];
                ACC(g0 & 7, v0); ACC(g1 & 7, v1); ACC(g2 & 7, v2); ACC(g3 & 7, v3);
                ACC(g4 & 7, v4); ACC(g5 & 7, v5); ACC(g6 & 7, v6); ACC(g7 & 7, v7);
            }
            float inv = invdeg[d];
            bf16x8 h;
            h[0] = (__bf16)(f0 * inv); h[1] = (__bf16)(f1 * inv);
            h[2] = (__bf16)(f2 * inv); h[3] = (__bf16)(f3 * inv);
            h[4] = (__bf16)(f4 * inv); h[5] = (__bf16)(f5 * inv);
            h[6] = (__bf16)(f6 * inv); h[7] = (__bf16)(f7 * inv);
            // k-permuted row: element k = ch*8 + r, lane holds ch=lane -> 16B contiguous
            *reinterpret_cast<bf16x8*>(&S[(wave * 4 + rr) * PADK + lane * 8]) = h;
        }
        __syncthreads();

        // ---------- phase B: 16x64 GEMM over K=576 ----------
        int n = tile * 16 + l15;
        int nc = (n < N) ? n : (N - 1);                   // clamped load, guarded store
        const __bf16* xrow = xb + (size_t)nc * DIM + lg * 8;
        const __bf16* srow = &S[l15 * PADK + lg * 8];

        f32x4 acc = (f32x4){0.f, 0.f, 0.f, 0.f};
#pragma unroll
        for (int kk = 0; kk < KS / 32; ++kk) {
            bf16x8 bv = *reinterpret_cast<const bf16x8*>(srow + kk * 32);
            acc = __builtin_amdgcn_mfma_f32_16x16x32_bf16(afrag[kk], bv, acc, 0, 0, 0);
        }
#pragma unroll
        for (int kk = 0; kk < DIM / 32; ++kk) {
            bf16x8 bv = *reinterpret_cast<const bf16x8*>(xrow + kk * 32);
            acc = __builtin_amdgcn_mfma_f32_16x16x32_bf16(afrag[KS / 32 + kk], bv, acc, 0, 0, 0);
        }

        if (n < N) {
            bf16x4 h;
#pragma unroll
            for (int i = 0; i < 4; ++i)
                h[i] = (__bf16)fmaxf(acc[i] + bias4[i], 0.f);
            *reinterpret_cast<bf16x4*>(xout + (size_t)n * DIM + cbase) = h;
        }
        __syncthreads();                                  // WAR: next tile rewrites S
    }
}

// ---------------- score ----------------
__global__ __launch_bounds__(256) void score_kernel(const __bf16* __restrict__ xb,
                                                    const int* __restrict__ s,
                                                    const int* __restrict__ t,
                                                    float* __restrict__ out, int T) {
    int i = blockIdx.x * 4 + (threadIdx.x >> 6);
    if (i >= T) return;
    int lane = threadIdx.x & 63;
    float p = (float)xb[(size_t)s[i] * DIM + lane] * (float)xb[(size_t)t[i] * DIM + lane];
#pragma unroll
    for (int off = 32; off > 0; off >>= 1) p += __shfl_down(p, off, 64);
    if (lane == 0) out[i] = p;
}

extern "C" void kernel_launch(void* const* d_in, const int* in_sizes, int n_in,
                              void* d_out, int out_size, void* d_ws, size_t ws_size,
                              hipStream_t stream) {
    const int*   x_idx  = (const int*)d_in[0];
    const int*   eidx   = (const int*)d_in[1];   // [2,E]
    const int*   etyp   = (const int*)d_in[2];   // [E]
    const int*   tidx   = (const int*)d_in[3];   // [2,T]
    const float* emb    = (const float*)d_in[4]; // [N,64]
    const float* weight = (const float*)d_in[5]; // [L,8,64,64]
    const float* root   = (const float*)d_in[6]; // [L,64,64]
    const float* bias   = (const float*)d_in[7]; // [L,64]

    int N = in_sizes[0];
    int E = in_sizes[2];
    int T = in_sizes[3] / 2;
    int L = in_sizes[5] / (NREL * DIM * DIM);

    const int* src = eidx;
    const int* dst = eidx + E;
    const int* ts  = tidx;
    const int* tt  = tidx + T;
    float* out = (float*)d_out;

    int epad_cap = E + 3 * N + 64;              // per-row pad <= 3, + step-8 over-read slack

    // ---- workspace carve-up ----
    char* p = (char*)d_ws;
    auto alloc = [&](size_t bytes) -> void* {
        void* r = (void*)p;
        p += (bytes + 255) & ~(size_t)255;
        return r;
    };
    __bf16* xb0     = (__bf16*)alloc((size_t)(N + 1) * DIM * sizeof(__bf16));  // +1 zero row
    __bf16* xb1     = (__bf16*)alloc((size_t)(N + 1) * DIM * sizeof(__bf16));  // ping-pong
    __bf16* Wt      = (__bf16*)alloc((size_t)L * 64 * KTOT * sizeof(__bf16));
    int*    srcs    = (int*)   alloc((size_t)epad_cap * sizeof(int));
    int*    eoff    = (int*)   alloc((size_t)E * sizeof(int));
    int*    deg8    = (int*)   alloc((size_t)N * 8 * sizeof(int));
    int*    rp      = (int*)   alloc(((size_t)N * 8 + 1) * sizeof(int));
    int*    offs    = (int*)   alloc((size_t)N * sizeof(int));
    float*  invdeg  = (float*) alloc((size_t)N * sizeof(float));
    int*    bsum    = (int*)   alloc(1024 * sizeof(int));

    int nb = (N + 255) / 256;

    hipMemsetAsync(deg8, 0, (size_t)N * 8 * sizeof(int), stream);
    histgather_kernel<<<((size_t)N * DIM + 255) / 256, 256, 0, stream>>>(
        dst, etyp, deg8, eoff, x_idx, emb, xb0, xb1, srcs, N, E, epad_cap);
    scan1_kernel<<<nb, 256, 0, stream>>>(deg8, offs, bsum, invdeg, N);
    {
        int wtotal = L * 64 * KTOT;
        int wblocks = 1 + (wtotal + 511) / 512;
        scan2wcat_kernel<<<wblocks, 512, 0, stream>>>(bsum, nb, weight, root, Wt, L);
    }
    rpbuild_kernel<<<nb, 256, 0, stream>>>(deg8, offs, bsum, rp, N);
    {
        int half = (E + 1) / 2;
        bucket_kernel<<<(half + 255) / 256, 256, 0, stream>>>(src, dst, etyp, rp, eoff, srcs, E);
    }

    __bf16* xcur = xb0;
    __bf16* xnxt = xb1;
    for (int l = 0; l < L; ++l) {
        aggemm2_kernel<<<2048, 256, 0, stream>>>(xcur, srcs, rp, invdeg,
                                                 Wt + (size_t)l * 64 * KTOT,
                                                 bias + (size_t)l * DIM,
                                                 xnxt, N);
        __bf16* tmp = xcur; xcur = xnxt; xnxt = tmp;
    }

    score_kernel<<<(T + 3) / 4, 256, 0, stream>>>(xcur, ts, tt, out, T);
}